// Round 1
// baseline (439.483 us; speedup 1.0000x reference)
//
#include <hip/hip_runtime.h>
#include <math.h>

#define NEG_SLOPE 0.2f

// ---------------------------------------------------------------- degree + edge-weight sum
__global__ void k_deg(const int* __restrict__ dst, const float* __restrict__ ew,
                      int* __restrict__ deg, float* __restrict__ sum_ea, int E) {
  int e = blockIdx.x * 256 + threadIdx.x;
  if (e >= E) return;
  int d = dst[e];
  atomicAdd(&deg[d], 1);
  atomicAdd(&sum_ea[d], ew[e]);
}

__global__ void k_mean(int n, const int* __restrict__ deg, float* __restrict__ sum_ea) {
  int v = blockIdx.x * 256 + threadIdx.x;
  if (v >= n) return;
  int c = deg[v];
  sum_ea[v] = sum_ea[v] / (float)(c > 1 ? c : 1);
}

// ---------------------------------------------------------------- exclusive scan of (deg+1) -> row_ptr
__global__ void k_scan(const int* __restrict__ deg, int* __restrict__ row_ptr, int n) {
  __shared__ int sums[1024];
  int t = threadIdx.x;
  int chunk = (n + 1023) >> 10;
  int begin = t * chunk; if (begin > n) begin = n;
  int end = begin + chunk; if (end > n) end = n;
  int s = 0;
  for (int i = begin; i < end; i++) s += deg[i] + 1;
  sums[t] = s;
  __syncthreads();
  for (int off = 1; off < 1024; off <<= 1) {
    int v = (t >= off) ? sums[t - off] : 0;
    __syncthreads();
    sums[t] += v;
    __syncthreads();
  }
  int offset = (t == 0) ? 0 : sums[t - 1];
  for (int i = begin; i < end; i++) { row_ptr[i] = offset; offset += deg[i] + 1; }
  if (t == 1023) row_ptr[n] = offset;
}

// ---------------------------------------------------------------- counting-sort edges (+self loops) into CSR
__global__ void k_scatter(const int* __restrict__ src, const int* __restrict__ dst,
                          const float* __restrict__ ew, const float* __restrict__ mean_ea,
                          const int* __restrict__ row_ptr, int* __restrict__ cursor,
                          int* __restrict__ col_src, int* __restrict__ col_dst,
                          float* __restrict__ col_w, int E, int n) {
  int e = blockIdx.x * 256 + threadIdx.x;
  if (e >= E + n) return;
  int s, d; float wv;
  if (e < E) { s = src[e]; d = dst[e]; wv = ew[e]; }
  else       { s = d = e - E; wv = mean_ea[e - E]; }
  int p = row_ptr[d] + atomicAdd(&cursor[d], 1);
  col_src[p] = s; col_dst[p] = d; col_w[p] = wv;
}

// ---------------------------------------------------------------- f32 GEMM: C[nrows x ncols] = A[nrows x 128] @ B[128 x ncols]
// 64-col tile in LDS; each thread: 2 rows x 4 cols.
__global__ __launch_bounds__(256) void k_gemm64(const float* __restrict__ A,
                                                const float* __restrict__ B,
                                                float* __restrict__ C,
                                                int nrows, int ncols) {
  __shared__ float Bs[128 * 64];
  int c0 = blockIdx.y * 64;
  for (int i = threadIdx.x; i < 128 * 16; i += 256) {   // 2048 float4 = 128x64
    int k = i >> 4;
    int c4 = (i & 15) << 2;
    *(float4*)&Bs[k * 64 + c4] = *(const float4*)&B[(size_t)k * ncols + c0 + c4];
  }
  __syncthreads();
  int rp = threadIdx.x >> 4;          // 0..15 row-pair
  int cq = (threadIdx.x & 15) << 2;   // col quad within 64
  int r0 = blockIdx.x * 32 + rp * 2, r1 = r0 + 1;
  bool v0 = r0 < nrows, v1 = r1 < nrows;
  const float* a0p = A + (size_t)(v0 ? r0 : 0) * 128;
  const float* a1p = A + (size_t)(v1 ? r1 : 0) * 128;
  float4 acc0 = {0,0,0,0}, acc1 = {0,0,0,0};
  #pragma unroll 8
  for (int k = 0; k < 128; k++) {
    float a0 = a0p[k];
    float a1 = a1p[k];
    float4 b = *(const float4*)&Bs[k * 64 + cq];
    acc0.x += a0 * b.x; acc0.y += a0 * b.y; acc0.z += a0 * b.z; acc0.w += a0 * b.w;
    acc1.x += a1 * b.x; acc1.y += a1 * b.y; acc1.z += a1 * b.z; acc1.w += a1 * b.w;
  }
  if (v0) *(float4*)&C[(size_t)r0 * ncols + c0 + cq] = acc0;
  if (v1) *(float4*)&C[(size_t)r1 * ncols + c0 + cq] = acc1;
}

// ---------------------------------------------------------------- per-(node,head) attention coefficients
template<int H>
__global__ void k_attn(const float* __restrict__ xs, const float* __restrict__ att_src,
                       const float* __restrict__ att_dst,
                       float* __restrict__ a_src, float* __restrict__ a_dst, int n) {
  int idx = blockIdx.x * 256 + threadIdx.x;
  if (idx >= n * H) return;
  int v = idx / H, h = idx % H;
  const float* row = xs + (size_t)v * (H * 64) + h * 64;
  float s1 = 0.f, s2 = 0.f;
  #pragma unroll
  for (int c = 0; c < 64; c += 4) {
    float4 xv = *(const float4*)(row + c);
    float4 as = *(const float4*)(att_src + h * 64 + c);
    float4 ad = *(const float4*)(att_dst + h * 64 + c);
    s1 += xv.x*as.x + xv.y*as.y + xv.z*as.z + xv.w*as.w;
    s2 += xv.x*ad.x + xv.y*ad.y + xv.z*ad.z + xv.w*ad.w;
  }
  a_src[idx] = s1; a_dst[idx] = s2;
}

// ---------------------------------------------------------------- edge-attention scalars: s1[0],s1[1],s2
__global__ void k_scalars(const float* __restrict__ We1, const float* __restrict__ ae1,
                          const float* __restrict__ We2, const float* __restrict__ ae2,
                          float* __restrict__ out) {
  int t = threadIdx.x;
  if (t == 0) { float s = 0; for (int c = 0; c < 64; c++) s += We1[c] * ae1[c]; out[0] = s; }
  if (t == 1) { float s = 0; for (int c = 0; c < 64; c++) s += We1[64 + c] * ae1[64 + c]; out[1] = s; }
  if (t == 2) { float s = 0; for (int c = 0; c < 64; c++) s += We2[c] * ae2[c]; out[2] = s; }
}

// ---------------------------------------------------------------- per-edge logits (layer 1, H=2)
__global__ void k_logits1(const int* __restrict__ col_src, const int* __restrict__ col_dst,
                          const float* __restrict__ col_w, const float* __restrict__ a_src,
                          const float* __restrict__ a_dst, const float* __restrict__ scal,
                          float* __restrict__ lg, int Etot) {
  int p = blockIdx.x * 256 + threadIdx.x;
  if (p >= Etot) return;
  int s = col_src[p], d = col_dst[p];
  float wv = col_w[p];
  float l0 = a_src[2 * s]     + a_dst[2 * d]     + wv * scal[0];
  float l1 = a_src[2 * s + 1] + a_dst[2 * d + 1] + wv * scal[1];
  lg[2 * p]     = l0 > 0.f ? l0 : NEG_SLOPE * l0;
  lg[2 * p + 1] = l1 > 0.f ? l1 : NEG_SLOPE * l1;
}

// ---------------------------------------------------------------- per-edge logits (layer 2, H=1)
__global__ void k_logits2(const int* __restrict__ col_src, const int* __restrict__ col_dst,
                          const float* __restrict__ col_w, const float* __restrict__ a_src,
                          const float* __restrict__ a_dst, const float* __restrict__ scal,
                          float* __restrict__ lg, int Etot) {
  int p = blockIdx.x * 256 + threadIdx.x;
  if (p >= Etot) return;
  float l = a_src[col_src[p]] + a_dst[col_dst[p]] + col_w[p] * scal[2];
  lg[p] = l > 0.f ? l : NEG_SLOPE * l;
}

// ---------------------------------------------------------------- warp-per-node softmax + aggregate, layer 1 (H=2, C=64) + bias + ELU
__global__ __launch_bounds__(256) void k_agg1(const int* __restrict__ row_ptr,
                                              const int* __restrict__ col_src,
                                              const float* __restrict__ lg,
                                              const float* __restrict__ xs,
                                              const float* __restrict__ b1,
                                              float* __restrict__ h_out, int n) {
  int wid = (blockIdx.x * 256 + threadIdx.x) >> 6;
  int lane = threadIdx.x & 63;
  if (wid >= n) return;
  int beg = row_ptr[wid], end = row_ptr[wid + 1];
  float m0 = -1e30f, m1 = -1e30f;
  for (int p = beg + lane; p < end; p += 64) {
    m0 = fmaxf(m0, lg[2 * p]); m1 = fmaxf(m1, lg[2 * p + 1]);
  }
  #pragma unroll
  for (int off = 32; off; off >>= 1) {
    m0 = fmaxf(m0, __shfl_xor(m0, off));
    m1 = fmaxf(m1, __shfl_xor(m1, off));
  }
  float d0 = 0.f, d1 = 0.f;
  for (int p = beg + lane; p < end; p += 64) {
    d0 += __expf(lg[2 * p] - m0);
    d1 += __expf(lg[2 * p + 1] - m1);
  }
  #pragma unroll
  for (int off = 32; off; off >>= 1) {
    d0 += __shfl_xor(d0, off);
    d1 += __shfl_xor(d1, off);
  }
  float i0 = 1.f / (d0 + 1e-16f), i1 = 1.f / (d1 + 1e-16f);
  float acc0 = 0.f, acc1 = 0.f;
  for (int p0 = beg; p0 < end; p0 += 64) {
    int p = p0 + lane;
    float w0 = 0.f, w1 = 0.f; int s = 0;
    if (p < end) {
      w0 = __expf(lg[2 * p] - m0) * i0;
      w1 = __expf(lg[2 * p + 1] - m1) * i1;
      s = col_src[p];
    }
    int cnt = end - p0; if (cnt > 64) cnt = 64;
    for (int j = 0; j < cnt; j++) {
      float a0 = __shfl(w0, j);
      float a1 = __shfl(w1, j);
      int   sj = __shfl(s, j);
      acc0 += a0 * xs[(size_t)sj * 128 + lane];
      acc1 += a1 * xs[(size_t)sj * 128 + 64 + lane];
    }
  }
  float o0 = acc0 + b1[lane];
  float o1 = acc1 + b1[64 + lane];
  o0 = o0 > 0.f ? o0 : expm1f(o0);   // ELU
  o1 = o1 > 0.f ? o1 : expm1f(o1);
  h_out[(size_t)wid * 128 + lane] = o0;
  h_out[(size_t)wid * 128 + 64 + lane] = o1;
}

// ---------------------------------------------------------------- warp-per-node softmax + aggregate, layer 2 (H=1, C=64) + bias
__global__ __launch_bounds__(256) void k_agg2(const int* __restrict__ row_ptr,
                                              const int* __restrict__ col_src,
                                              const float* __restrict__ lg,
                                              const float* __restrict__ xs,
                                              const float* __restrict__ b2,
                                              float* __restrict__ out, int n) {
  int wid = (blockIdx.x * 256 + threadIdx.x) >> 6;
  int lane = threadIdx.x & 63;
  if (wid >= n) return;
  int beg = row_ptr[wid], end = row_ptr[wid + 1];
  float m = -1e30f;
  for (int p = beg + lane; p < end; p += 64) m = fmaxf(m, lg[p]);
  #pragma unroll
  for (int off = 32; off; off >>= 1) m = fmaxf(m, __shfl_xor(m, off));
  float dsum = 0.f;
  for (int p = beg + lane; p < end; p += 64) dsum += __expf(lg[p] - m);
  #pragma unroll
  for (int off = 32; off; off >>= 1) dsum += __shfl_xor(dsum, off);
  float inv = 1.f / (dsum + 1e-16f);
  float acc = 0.f;
  for (int p0 = beg; p0 < end; p0 += 64) {
    int p = p0 + lane;
    float wv = 0.f; int s = 0;
    if (p < end) { wv = __expf(lg[p] - m) * inv; s = col_src[p]; }
    int cnt = end - p0; if (cnt > 64) cnt = 64;
    for (int j = 0; j < cnt; j++) {
      float aj = __shfl(wv, j);
      int   sj = __shfl(s, j);
      acc += aj * xs[(size_t)sj * 64 + lane];
    }
  }
  out[(size_t)wid * 64 + lane] = acc + b2[lane];
}

// ================================================================ launch
extern "C" void kernel_launch(void* const* d_in, const int* in_sizes, int n_in,
                              void* d_out, int out_size, void* d_ws, size_t ws_size,
                              hipStream_t stream) {
  const float* x   = (const float*)d_in[0];
  const int*   ei  = (const int*)d_in[1];
  const float* ew  = (const float*)d_in[2];
  const float* W1  = (const float*)d_in[3];
  const float* as1 = (const float*)d_in[4];
  const float* ad1 = (const float*)d_in[5];
  const float* We1 = (const float*)d_in[6];
  const float* ae1 = (const float*)d_in[7];
  const float* b1  = (const float*)d_in[8];
  const float* W2  = (const float*)d_in[9];
  const float* as2 = (const float*)d_in[10];
  const float* ad2 = (const float*)d_in[11];
  const float* We2 = (const float*)d_in[12];
  const float* ae2 = (const float*)d_in[13];
  const float* b2  = (const float*)d_in[14];

  const int n = in_sizes[0] / 128;
  const int E = in_sizes[1] / 2;
  const int Etot = E + n;

  char* wsb = (char*)d_ws;
  size_t off = 0;
  auto alloc = [&](size_t bytes) -> void* {
    void* p = wsb + off; off += (bytes + 255) & ~(size_t)255; return p;
  };
  int*   deg     = (int*)  alloc((size_t)n * 4);
  float* mean_ea = (float*)alloc((size_t)n * 4);
  int*   row_ptr = (int*)  alloc((size_t)(n + 1) * 4);
  int*   cursor  = (int*)  alloc((size_t)n * 4);
  int*   col_src = (int*)  alloc((size_t)Etot * 4);
  int*   col_dst = (int*)  alloc((size_t)Etot * 4);
  float* col_w   = (float*)alloc((size_t)Etot * 4);
  float* lg      = (float*)alloc((size_t)Etot * 8);     // layer1: 2 heads; reused layer2
  float* xs1     = (float*)alloc((size_t)n * 128 * 4);  // reused as xs2
  float* h1      = (float*)alloc((size_t)n * 128 * 4);
  float* a_src1v = (float*)alloc((size_t)n * 2 * 4);
  float* a_dst1v = (float*)alloc((size_t)n * 2 * 4);
  float* a_src2v = (float*)alloc((size_t)n * 4);
  float* a_dst2v = (float*)alloc((size_t)n * 4);
  float* scal    = (float*)alloc(64);
  if (off > ws_size) return;  // workspace too small -> fail visibly, no corruption

  hipMemsetAsync(deg, 0, (size_t)n * 4, stream);
  hipMemsetAsync(mean_ea, 0, (size_t)n * 4, stream);
  hipMemsetAsync(cursor, 0, (size_t)n * 4, stream);

  dim3 B(256);
  k_deg<<<dim3((E + 255) / 256), B, 0, stream>>>(ei + E, ew, deg, mean_ea, E);
  k_mean<<<dim3((n + 255) / 256), B, 0, stream>>>(n, deg, mean_ea);
  k_scan<<<1, 1024, 0, stream>>>(deg, row_ptr, n);
  k_scatter<<<dim3((Etot + 255) / 256), B, 0, stream>>>(ei, ei + E, ew, mean_ea, row_ptr,
                                                        cursor, col_src, col_dst, col_w, E, n);
  // layer 1
  k_gemm64<<<dim3((n + 31) / 32, 2), B, 0, stream>>>(x, W1, xs1, n, 128);
  k_attn<2><<<dim3((2 * n + 255) / 256), B, 0, stream>>>(xs1, as1, ad1, a_src1v, a_dst1v, n);
  k_scalars<<<1, 64, 0, stream>>>(We1, ae1, We2, ae2, scal);
  k_logits1<<<dim3((Etot + 255) / 256), B, 0, stream>>>(col_src, col_dst, col_w,
                                                        a_src1v, a_dst1v, scal, lg, Etot);
  k_agg1<<<dim3((n * 64 + 255) / 256), B, 0, stream>>>(row_ptr, col_src, lg, xs1, b1, h1, n);
  // layer 2
  k_gemm64<<<dim3((n + 31) / 32, 1), B, 0, stream>>>(h1, W2, xs1, n, 64);
  k_attn<1><<<dim3((n + 255) / 256), B, 0, stream>>>(xs1, as2, ad2, a_src2v, a_dst2v, n);
  k_logits2<<<dim3((Etot + 255) / 256), B, 0, stream>>>(col_src, col_dst, col_w,
                                                        a_src2v, a_dst2v, scal, lg, Etot);
  k_agg2<<<dim3((n * 64 + 255) / 256), B, 0, stream>>>(row_ptr, col_src, lg, xs1, b2,
                                                       (float*)d_out, n);
}